// Round 14
// baseline (1113.216 us; speedup 1.0000x reference)
//
#include <hip/hip_runtime.h>
#include <hip/hip_bf16.h>

typedef __bf16 bf16;
typedef __attribute__((ext_vector_type(8))) __bf16 bf16x8;
typedef __attribute__((ext_vector_type(4))) float f32x4;

union BP { unsigned u; bf16 b[2]; };

#define SB() __builtin_amdgcn_sched_barrier(0)

// async global->LDS DMA, 16B per lane.  LDS dest is wave-uniform base +
// lane*16 (HW rule); global src is per-lane.  Tracked by vmcnt.
__device__ __forceinline__ void dma16(const void* g, void* l) {
  __builtin_amdgcn_global_load_lds(
      (const __attribute__((address_space(1))) unsigned*)g,
      (__attribute__((address_space(3))) unsigned*)l, 16, 0, 0);
}

// ---------------------------------------------------------------------------
// fused step kernel (ROUND-14): gather + GEMMs + GRU in ONE kernel.
//   phase 0 (if do_gather): each wave gathers/aggregates the 32 nodes whose
//     rows IT will consume in pass-1 (wave-local dependency), writes aggH
//     tile rows to `big` (L2-hot for the immediate re-read), __syncthreads
//     (drains vmcnt -> counted-wait bookkeeping below stays valid).
//   then: verified round-9 body (pass-1 K=544, gates, GRU), h' -> hbout.
// agg_k/fused ran sequentially per step (75+85us) on DISJOINT resources
// (memory-latency vs MFMA+L2); co-resident blocks (3/CU) now overlap the
// phases.  RACE NOTE: h' writes (tile-local, hbout) vs other blocks'
// gather reads (global, hbin) -> host ping-pongs h between two buffers.
// Fallback (ws too small): host runs agg_k + this kernel with do_gather=0
// and hbin==hbout (safe: non-gather body touches only tile-local h rows).
// hbin/hbout deliberately NOT __restrict__ (they alias in fallback mode).
// ---------------------------------------------------------------------------
__global__ __launch_bounds__(256) void fused2_k(bf16* __restrict__ big,
                                                const bf16* hbin,
                                                bf16* hbout,
                                                const bf16* __restrict__ wb,
                                                const int* __restrict__ rp,
                                                const int* __restrict__ bkt,
                                                int M, int do_gather)
{
  const int lane = threadIdx.x & 63;
  const int w    = threadIdx.x >> 6;
  const int quad = lane >> 4;
  const int lr   = lane & 15;
  const int mbase = blockIdx.x * 128 + w * 32;

  __shared__ __align__(16) bf16 lds[128 * 136];
  __shared__ __align__(16) bf16 wlds[2][4096];

  // ---- phase 0: gather own tile's aggH rows (round-8 verified agg body) --
  if (do_gather) {
    const unsigned* hp = (const unsigned*)hbin;
#pragma unroll 1
    for (int ii = 0; ii < 32; ++ii) {
      const int n = blockIdx.x * 128 + w * 32 + ii;
      if (n >= M) break;
      unsigned* outp = (unsigned*)big + (size_t)n * 272;
      const int e0 = rp[n * 4];
      const int e1 = rp[n * 4 + 1];
      const int e2 = rp[n * 4 + 2];
      const int e3 = rp[n * 4 + 3];
      const int e4 = rp[n * 4 + 4];
      float t0 = 0.f, t1 = 0.f;
      float s10 = 0.f, s11 = 0.f, s20 = 0.f, s21 = 0.f, s30 = 0.f, s31 = 0.f;
      int base = e0;
      for (; base + 8 <= e4; base += 8) {
        unsigned u[8];
#pragma unroll
        for (int t = 0; t < 8; ++t)
          u[t] = hp[(unsigned)bkt[base + t] * 64u + (unsigned)lane];
#pragma unroll
        for (int t = 0; t < 8; ++t) {
          const int i = base + t;
          t0 += __uint_as_float(u[t] << 16);
          t1 += __uint_as_float(u[t] & 0xffff0000u);
          s10 = (i < e1) ? t0 : s10;  s11 = (i < e1) ? t1 : s11;
          s20 = (i < e2) ? t0 : s20;  s21 = (i < e2) ? t1 : s21;
          s30 = (i < e3) ? t0 : s30;  s31 = (i < e3) ? t1 : s31;
        }
      }
      if (base < e4) {
        const int last = e4 - 1;
        unsigned u[8];
#pragma unroll
        for (int t = 0; t < 8; ++t) {
          int i = base + t; i = i <= last ? i : last;
          u[t] = hp[(unsigned)bkt[i] * 64u + (unsigned)lane];
        }
#pragma unroll
        for (int t = 0; t < 8; ++t) {
          const int i = base + t;
          const bool ok = (i <= last);
          const float v0 = __uint_as_float(u[t] << 16);
          const float v1 = __uint_as_float(u[t] & 0xffff0000u);
          t0 += ok ? v0 : 0.f;
          t1 += ok ? v1 : 0.f;
          s10 = (i < e1) ? t0 : s10;  s11 = (i < e1) ? t1 : s11;
          s20 = (i < e2) ? t0 : s20;  s21 = (i < e2) ? t1 : s21;
          s30 = (i < e3) ? t0 : s30;  s31 = (i < e3) ? t1 : s31;
        }
      }
      BP o;
      o.b[0] = (bf16)s10;         o.b[1] = (bf16)s11;         outp[0 * 64 + lane] = o.u;
      o.b[0] = (bf16)(s20 - s10); o.b[1] = (bf16)(s21 - s11); outp[1 * 64 + lane] = o.u;
      o.b[0] = (bf16)(s30 - s20); o.b[1] = (bf16)(s31 - s21); outp[2 * 64 + lane] = o.u;
      o.b[0] = (bf16)(t0 - s30);  o.b[1] = (bf16)(t1 - s31);  outp[3 * 64 + lane] = o.u;
      if (lane < 16) {
        BP z; z.b[0] = (bf16)0.f; z.b[1] = (bf16)0.f;
        if (lane == 0) { z.b[0] = (bf16)(float)(e1 - e0); z.b[1] = (bf16)(float)(e2 - e1); }
        if (lane == 1) { z.b[0] = (bf16)(float)(e3 - e2); z.b[1] = (bf16)(float)(e4 - e3); }
        outp[256 + lane] = z.u;
      }
    }
    __syncthreads();   // drains gather stores; vmcnt clean for counted waits
  }

  const bf16* wcat = wb;
  const bf16* blk  = wb + 69632;
  const bf16 *ih0 = blk,             *ih1 = blk + 16384, *ihn = blk + 2 * 16384;
  const bf16 *hh0 = blk + 3 * 16384, *hh1 = blk + 4 * 16384, *hhn = blk + 5 * 16384;
  const bf16 *bih = wb + 217088, *bhh = wb + 217472;

  long r0 = mbase + lr;      if (r0 >= M) r0 = M - 1;
  long r1 = mbase + 16 + lr; if (r1 >= M) r1 = M - 1;

  // ---- pass-1 prologue: issue group 0 (2 DMA + 2 A-loads = 4 vmcnt events)
  dma16(wcat + (size_t)(w * 2)     * 512 + (size_t)lane * 8, &wlds[0][(w * 2) * 512]);
  dma16(wcat + (size_t)(w * 2 + 1) * 512 + (size_t)lane * 8, &wlds[0][(w * 2 + 1) * 512]);
  bf16x8 Ab[2][2];
  Ab[0][0] = *(const bf16x8*)(big + r0 * 544 + quad * 8);
  Ab[0][1] = *(const bf16x8*)(big + r1 * 544 + quad * 8);

  f32x4 acc[2][8];
#pragma unroll
  for (int i = 0; i < 2; ++i)
#pragma unroll
    for (int j = 0; j < 8; ++j) acc[i][j] = (f32x4){0.f, 0.f, 0.f, 0.f};

  // ---- pass 1: a-tile (K=544); counted-vmcnt double-buffer pipeline ----
#pragma unroll
  for (int kk = 0; kk < 17; ++kk) {
    const int cur = kk & 1;
    const int nxt = cur ^ 1;
    if (kk + 1 < 17) {
      const size_t gb = (size_t)(kk + 1) * 4096;
      dma16(wcat + gb + (size_t)(w * 2)     * 512 + (size_t)lane * 8, &wlds[nxt][(w * 2) * 512]);
      dma16(wcat + gb + (size_t)(w * 2 + 1) * 512 + (size_t)lane * 8, &wlds[nxt][(w * 2 + 1) * 512]);
      const int kc = (kk + 1) * 32 + quad * 8;
      Ab[nxt][0] = *(const bf16x8*)(big + r0 * 544 + kc);
      Ab[nxt][1] = *(const bf16x8*)(big + r1 * 544 + kc);
    }
    SB();
    if (kk + 1 < 17) asm volatile("s_waitcnt vmcnt(4)" ::: "memory");
    else             asm volatile("s_waitcnt vmcnt(0)" ::: "memory");
    SB();
    __builtin_amdgcn_s_barrier();      // all waves' group-kk DMAs landed
    SB();
    __builtin_amdgcn_s_setprio(1);
#pragma unroll
    for (int ct = 0; ct < 8; ++ct) {
      bf16x8 b = *(const bf16x8*)&wlds[cur][(ct * 64 + lane) * 8];
      acc[0][ct] = __builtin_amdgcn_mfma_f32_16x16x32_bf16(Ab[cur][0], b, acc[0][ct], 0, 0, 0);
      acc[1][ct] = __builtin_amdgcn_mfma_f32_16x16x32_bf16(Ab[cur][1], b, acc[1][ct], 0, 0, 0);
    }
    __builtin_amdgcn_s_setprio(0);
    SB();
    __builtin_amdgcn_s_barrier();      // all waves done reading wlds[cur]
    SB();
  }

  // ---- gates prologue: DMA group (ch=0,kk=0) into buf0 ----
  const bf16* wptr0 = ih0; const bf16* wptr1 = hh0; const bf16* wptr2 = ih1;
  const bf16* wptr3 = hh1; const bf16* wptr4 = ihn; const bf16* wptr5 = hhn;
  {
    if (w == 0) { dma16(wptr0 + (size_t)lane * 8, &wlds[0][0 * 512]);
                  dma16(wptr4 + (size_t)lane * 8, &wlds[0][4 * 512]); }
    if (w == 1) { dma16(wptr1 + (size_t)lane * 8, &wlds[0][1 * 512]);
                  dma16(wptr5 + (size_t)lane * 8, &wlds[0][5 * 512]); }
    if (w == 2) { dma16(wptr2 + (size_t)lane * 8, &wlds[0][2 * 512]); }
    if (w == 3) { dma16(wptr3 + (size_t)lane * 8, &wlds[0][3 * 512]); }
  }

  // h fragments (from hbin)
  bf16x8 hf[2][4];
#pragma unroll
  for (int kk = 0; kk < 4; ++kk) {
    hf[0][kk] = *(const bf16x8*)(hbin + r0 * 128 + kk * 32 + quad * 8);
    hf[1][kk] = *(const bf16x8*)(hbin + r1 * 128 + kk * 32 + quad * 8);
  }
  // stage a-tile to LDS (wave-private rows; C/D-layout transpose)
#pragma unroll
  for (int ct = 0; ct < 8; ++ct) {
    const int nl = ct * 16 + lr;
#pragma unroll
    for (int rt = 0; rt < 2; ++rt) {
      const int rowb = w * 32 + rt * 16 + quad * 4;
#pragma unroll
      for (int r = 0; r < 4; ++r)
        lds[(rowb + r) * 136 + nl] = (bf16)acc[rt][ct][r];
    }
  }
  // wave reads only its own rows back -> ordered by lgkmcnt, no barrier
  bf16x8 af[2][4];
#pragma unroll
  for (int kk = 0; kk < 4; ++kk) {
    af[0][kk] = *(const bf16x8*)(lds + (w * 32 + lr) * 136 + kk * 32 + quad * 8);
    af[1][kk] = *(const bf16x8*)(lds + (w * 32 + 16 + lr) * 136 + kk * 32 + quad * 8);
  }
  // overwrite own rows with h-tile (row-major) for C/D-layout hv reads
#pragma unroll
  for (int kk = 0; kk < 4; ++kk) {
    *(bf16x8*)(lds + (w * 32 + lr) * 136 + kk * 32 + quad * 8)      = hf[0][kk];
    *(bf16x8*)(lds + (w * 32 + 16 + lr) * 136 + kk * 32 + quad * 8) = hf[1][kk];
  }
  __syncthreads();   // full drain: gates DMA(0) + hf loads + staging writes

  // ---- gates: 8 ch (rolled) x 4 kk (unrolled) counted-vmcnt phases ----
#pragma unroll 1
  for (int ch = 0; ch < 8; ++ch) {
    f32x4 c[4][2];   // [slice][rowfrag]: s0=r, s1=z, s2=in, s3=hn
#pragma unroll
    for (int s = 0; s < 4; ++s)
#pragma unroll
      for (int i = 0; i < 2; ++i) c[s][i] = (f32x4){0.f, 0.f, 0.f, 0.f};

#pragma unroll
    for (int kk = 0; kk < 4; ++kk) {
      const int cur = kk & 1;
      const int nx  = cur ^ 1;
      // issue next group; ALWAYS issue (clamped at the very end) so the
      // per-wave vmcnt event count stays uniform across phases
      {
        size_t koff;
        if (kk < 3) koff = (size_t)((kk + 1) * 8 + ch) * 512;
        else        koff = (size_t)(ch < 7 ? ch + 1 : 7) * 512;  // (kk=0, ct=ch+1); ch=7: dummy
        if (w == 0) { dma16(wptr0 + koff + (size_t)lane * 8, &wlds[nx][0 * 512]);
                      dma16(wptr4 + koff + (size_t)lane * 8, &wlds[nx][4 * 512]); }
        if (w == 1) { dma16(wptr1 + koff + (size_t)lane * 8, &wlds[nx][1 * 512]);
                      dma16(wptr5 + koff + (size_t)lane * 8, &wlds[nx][5 * 512]); }
        if (w == 2) { dma16(wptr2 + koff + (size_t)lane * 8, &wlds[nx][2 * 512]); }
        if (w == 3) { dma16(wptr3 + koff + (size_t)lane * 8, &wlds[nx][3 * 512]); }
      }
      SB();
      if (w < 2) asm volatile("s_waitcnt vmcnt(2)" ::: "memory");
      else       asm volatile("s_waitcnt vmcnt(1)" ::: "memory");
      SB();
      __builtin_amdgcn_s_barrier();    // all waves' current group landed
      SB();
      // consume current group from LDS
      bf16x8 g0 = *(const bf16x8*)&wlds[cur][(0 * 64 + lane) * 8];
      bf16x8 g1 = *(const bf16x8*)&wlds[cur][(1 * 64 + lane) * 8];
      bf16x8 g2 = *(const bf16x8*)&wlds[cur][(2 * 64 + lane) * 8];
      bf16x8 g3 = *(const bf16x8*)&wlds[cur][(3 * 64 + lane) * 8];
      bf16x8 g4 = *(const bf16x8*)&wlds[cur][(4 * 64 + lane) * 8];
      bf16x8 g5 = *(const bf16x8*)&wlds[cur][(5 * 64 + lane) * 8];
      __builtin_amdgcn_s_setprio(1);
      c[0][0] = __builtin_amdgcn_mfma_f32_16x16x32_bf16(af[0][kk], g0, c[0][0], 0, 0, 0);
      c[0][1] = __builtin_amdgcn_mfma_f32_16x16x32_bf16(af[1][kk], g0, c[0][1], 0, 0, 0);
      c[0][0] = __builtin_amdgcn_mfma_f32_16x16x32_bf16(hf[0][kk], g1, c[0][0], 0, 0, 0);
      c[0][1] = __builtin_amdgcn_mfma_f32_16x16x32_bf16(hf[1][kk], g1, c[0][1], 0, 0, 0);
      c[1][0] = __builtin_amdgcn_mfma_f32_16x16x32_bf16(af[0][kk], g2, c[1][0], 0, 0, 0);
      c[1][1] = __builtin_amdgcn_mfma_f32_16x16x32_bf16(af[1][kk], g2, c[1][1], 0, 0, 0);
      c[1][0] = __builtin_amdgcn_mfma_f32_16x16x32_bf16(hf[0][kk], g3, c[1][0], 0, 0, 0);
      c[1][1] = __builtin_amdgcn_mfma_f32_16x16x32_bf16(hf[1][kk], g3, c[1][1], 0, 0, 0);
      c[2][0] = __builtin_amdgcn_mfma_f32_16x16x32_bf16(af[0][kk], g4, c[2][0], 0, 0, 0);
      c[2][1] = __builtin_amdgcn_mfma_f32_16x16x32_bf16(af[1][kk], g4, c[2][1], 0, 0, 0);
      c[3][0] = __builtin_amdgcn_mfma_f32_16x16x32_bf16(hf[0][kk], g5, c[3][0], 0, 0, 0);
      c[3][1] = __builtin_amdgcn_mfma_f32_16x16x32_bf16(hf[1][kk], g5, c[3][1], 0, 0, 0);
      __builtin_amdgcn_s_setprio(0);

      if (kk == 3) {
        // GRU nonlinearity in registers; hv from LDS (wave-private rows)
        const int col = ch * 16 + lr;
        const float br = (float)bih[col]       + (float)bhh[col];
        const float bz = (float)bih[128 + col] + (float)bhh[128 + col];
        const float bi = (float)bih[256 + col];
        const float bh = (float)bhh[256 + col];
#pragma unroll
        for (int rt = 0; rt < 2; ++rt) {
          const int rowb = w * 32 + rt * 16 + quad * 4;
#pragma unroll
          for (int r = 0; r < 4; ++r) {
            const int li = (rowb + r) * 136 + col;
            const float hv = (float)lds[li];
            const float rr = 1.f / (1.f + __expf(-(c[0][rt][r] + br)));
            const float zz = 1.f / (1.f + __expf(-(c[1][rt][r] + bz)));
            const float xn = c[2][rt][r] + bi + rr * (c[3][rt][r] + bh);
            const float e2 = __expf(2.f * xn);
            const float nn = 1.f - 2.f / (e2 + 1.f);   // tanh(xn)
            lds[li] = (bf16)((1.f - zz) * nn + zz * hv);
          }
        }
      }
      SB();
      __builtin_amdgcn_s_barrier();    // all waves done reading wlds[cur]
      SB();
    }
  }

  __syncthreads();   // full drain (vm + lgkm) before cross-wave h' readback
  // coalesced h' store -> hbout
  const int tr = threadIdx.x >> 4;
  const int tc = (threadIdx.x & 15) * 8;
#pragma unroll
  for (int i = 0; i < 8; ++i) {
    const int row = i * 16 + tr;
    const int grow = blockIdx.x * 128 + row;
    if (grow < M) {
      bf16x8 v = *(const bf16x8*)(lds + row * 136 + tc);
      *(bf16x8*)(hbout + (size_t)grow * 128 + tc) = v;
    }
  }
}

// ---------------------------------------------------------------------------
// fused output head (round-13, verified): gl = hb@iwa + feat@iwb + ib,
// u = hb@jw + jb, out = u*sigmoid(gl); f32 intermediates.
// ---------------------------------------------------------------------------
__global__ __launch_bounds__(256) void headf_k(const bf16* __restrict__ hbp,
                                               const void* __restrict__ featp,
                                               const bf16* __restrict__ wb,
                                               void* __restrict__ outp, int M,
                                               const int* __restrict__ flagp)
{
  const int lane = threadIdx.x & 63;
  const int w    = threadIdx.x >> 6;
  const int quad = lane >> 4;
  const int lr   = lane & 15;
  const int mbase = blockIdx.x * 128 + w * 32;

  __shared__ __align__(16) bf16 lds[128 * 136];
  __shared__ __align__(16) bf16 wlds[2][1536];

  const bf16* blk = wb + 69632;
  const bf16 *iwa = blk + 6 * 16384, *iwb = blk + 7 * 16384, *jw = blk + 8 * 16384;
  const bf16 *ib = wb + 217856, *jb = wb + 217984;
  const bool f32o = (*flagp != 0);

  long r0 = mbase + lr;      if (r0 >= M) r0 = M - 1;
  long r1 = mbase + 16 + lr; if (r1 >= M) r1 = M - 1;

  if (w == 0) dma16(iwa + (size_t)lane * 8, &wlds[0][0 * 512]);
  if (w == 1) dma16(iwb + (size_t)lane * 8, &wlds[0][1 * 512]);
  if (w == 2) dma16(jw  + (size_t)lane * 8, &wlds[0][2 * 512]);

  bf16x8 hf[2][4], ff[2][4];
#pragma unroll
  for (int kk = 0; kk < 4; ++kk) {
    hf[0][kk] = *(const bf16x8*)(hbp + r0 * 128 + kk * 32 + quad * 8);
    hf[1][kk] = *(const bf16x8*)(hbp + r1 * 128 + kk * 32 + quad * 8);
  }
  if (f32o) {
    const float* F = (const float*)featp;
#pragma unroll
    for (int kk = 0; kk < 4; ++kk) {
      const int kc = kk * 32 + quad * 8;
      f32x4 x0 = *(const f32x4*)(F + r0 * 128 + kc);
      f32x4 x1 = *(const f32x4*)(F + r0 * 128 + kc + 4);
      f32x4 y0 = *(const f32x4*)(F + r1 * 128 + kc);
      f32x4 y1 = *(const f32x4*)(F + r1 * 128 + kc + 4);
#pragma unroll
      for (int i = 0; i < 4; ++i) {
        ff[0][kk][i] = (bf16)x0[i]; ff[0][kk][i + 4] = (bf16)x1[i];
        ff[1][kk][i] = (bf16)y0[i]; ff[1][kk][i + 4] = (bf16)y1[i];
      }
    }
  } else {
    const bf16* F = (const bf16*)featp;
#pragma unroll
    for (int kk = 0; kk < 4; ++kk) {
      ff[0][kk] = *(const bf16x8*)(F + r0 * 128 + kk * 32 + quad * 8);
      ff[1][kk] = *(const bf16x8*)(F + r1 * 128 + kk * 32 + quad * 8);
    }
  }
  __syncthreads();   // full drain: DMA(0) + fragment loads

#pragma unroll 1
  for (int ch = 0; ch < 8; ++ch) {
    f32x4 cg[2], cu[2];
#pragma unroll
    for (int i = 0; i < 2; ++i) { cg[i] = (f32x4){0.f, 0.f, 0.f, 0.f};
                                  cu[i] = (f32x4){0.f, 0.f, 0.f, 0.f}; }
#pragma unroll
    for (int kk = 0; kk < 4; ++kk) {
      const int cur = kk & 1;
      const int nx  = cur ^ 1;
      {
        size_t koff;
        if (kk < 3) koff = (size_t)((kk + 1) * 8 + ch) * 512;
        else        koff = (size_t)(ch < 7 ? ch + 1 : 7) * 512;  // (kk=0); ch=7: dummy
        if (w == 0) dma16(iwa + koff + (size_t)lane * 8, &wlds[nx][0 * 512]);
        if (w == 1) dma16(iwb + koff + (size_t)lane * 8, &wlds[nx][1 * 512]);
        if (w == 2) dma16(jw  + koff + (size_t)lane * 8, &wlds[nx][2 * 512]);
      }
      SB();
      if (w < 3) asm volatile("s_waitcnt vmcnt(1)" ::: "memory");
      else       asm volatile("s_waitcnt vmcnt(0)" ::: "memory");
      SB();
      __builtin_amdgcn_s_barrier();    // all waves' current group landed
      SB();
      bf16x8 g0 = *(const bf16x8*)&wlds[cur][(0 * 64 + lane) * 8];
      bf16x8 g1 = *(const bf16x8*)&wlds[cur][(1 * 64 + lane) * 8];
      bf16x8 g2 = *(const bf16x8*)&wlds[cur][(2 * 64 + lane) * 8];
      __builtin_amdgcn_s_setprio(1);
      cg[0] = __builtin_amdgcn_mfma_f32_16x16x32_bf16(hf[0][kk], g0, cg[0], 0, 0, 0);
      cg[1] = __builtin_amdgcn_mfma_f32_16x16x32_bf16(hf[1][kk], g0, cg[1], 0, 0, 0);
      cg[0] = __builtin_amdgcn_mfma_f32_16x16x32_bf16(ff[0][kk], g1, cg[0], 0, 0, 0);
      cg[1] = __builtin_amdgcn_mfma_f32_16x16x32_bf16(ff[1][kk], g1, cg[1], 0, 0, 0);
      cu[0] = __builtin_amdgcn_mfma_f32_16x16x32_bf16(hf[0][kk], g2, cu[0], 0, 0, 0);
      cu[1] = __builtin_amdgcn_mfma_f32_16x16x32_bf16(hf[1][kk], g2, cu[1], 0, 0, 0);
      __builtin_amdgcn_s_setprio(0);

      if (kk == 3) {
        const int col = ch * 16 + lr;
        const float bg = (float)ib[col];
        const float bu = (float)jb[col];
#pragma unroll
        for (int rt = 0; rt < 2; ++rt) {
          const int rowb = w * 32 + rt * 16 + quad * 4;
#pragma unroll
          for (int r = 0; r < 4; ++r) {
            const float gl = cg[rt][r] + bg;
            const float uu = cu[rt][r] + bu;
            const float val = uu / (1.f + expf(-gl));
            if (f32o) {
              const int grow = blockIdx.x * 128 + rowb + r;
              if (grow < M)
                ((float*)outp)[(size_t)grow * 128 + col] = val;
            } else {
              lds[(rowb + r) * 136 + col] = (bf16)val;
            }
          }
        }
      }
      SB();
      __builtin_amdgcn_s_barrier();    // all waves done reading wlds[cur]
      SB();
    }
  }

  __syncthreads();
  if (!f32o) {
    const int tr = threadIdx.x >> 4;
    const int tc = (threadIdx.x & 15) * 8;
#pragma unroll
    for (int i = 0; i < 8; ++i) {
      const int row = i * 16 + tr;
      const int grow = blockIdx.x * 128 + row;
      if (grow < M) {
        bf16x8 v = *(const bf16x8*)(lds + row * 136 + tc);
        *(bf16x8*)((bf16*)outp + (size_t)grow * 128 + tc) = v;
      }
    }
  }
}

// ---------------------------------------------------------------------------
__global__ __launch_bounds__(256) void detect_k(const unsigned short* __restrict__ f,
                                                int n16, int* __restrict__ flag)
{
  int i = blockIdx.x * 256 + threadIdx.x;
  int bad = 0;
  for (int j = i; j < n16; j += 256 * 1024) {
    int ex = (f[j] >> 7) & 0xFF;
    if (ex >= 0x87) bad = 1;
  }
  if (bad) atomicAdd(flag, 1);
}

__global__ __launch_bounds__(256) void feat_k(const void* __restrict__ src,
                                              bf16* __restrict__ hb, int n,
                                              const int* __restrict__ flag)
{
  int i = blockIdx.x * 256 + threadIdx.x;
  if (i >= n) return;
  if (*flag) hb[i] = (bf16)((const float*)src)[i];
  else       hb[i] = ((const bf16*)src)[i];
}

// ---------------------------------------------------------------------------
__global__ __launch_bounds__(256) void cvtw_k(
    const void* w_et, const void* b_et, const void* w_ih, const void* b_ih,
    const void* w_hh, const void* b_hh, const void* i_w, const void* i_b,
    const void* j_w, const void* j_b, bf16* __restrict__ wb,
    const int* __restrict__ flagp)
{
  int i = blockIdx.x * 256 + threadIdx.x;
  if (i >= 218112) return;
  const bool f32 = (*flagp != 0);
  auto rd = [&](const void* p, int idx) -> float {
    return f32 ? ((const float*)p)[idx] : (float)((const bf16*)p)[idx];
  };
  float v;
  if (i < 69632) {
    int e = i, j = e & 7, lane = (e >> 3) & 63, ct = (e >> 9) & 7, kk = e >> 12;
    int n = ct * 16 + (lane & 15), k = kk * 32 + (lane >> 4) * 8 + j;
    if (k < 512)      v = rd(w_et, (k >> 7) * 16384 + n * 128 + (k & 127));
    else if (k < 516) v = rd(b_et, (k - 512) * 128 + n);
    else              v = 0.f;
  } else if (i < 217088) {
    int blk = (i - 69632) >> 14, e = (i - 69632) & 16383;
    int j = e & 7, lane = (e >> 3) & 63, ct = (e >> 9) & 7, kk = e >> 12;
    int n = ct * 16 + (lane & 15), k = kk * 32 + (lane >> 4) * 8 + j;
    const void* src; int idx;
    switch (blk) {
      case 0: src = w_ih; idx = n * 128 + k; break;
      case 1: src = w_ih; idx = (128 + n) * 128 + k; break;
      case 2: src = w_ih; idx = (256 + n) * 128 + k; break;
      case 3: src = w_hh; idx = n * 128 + k; break;
      case 4: src = w_hh; idx = (128 + n) * 128 + k; break;
      case 5: src = w_hh; idx = (256 + n) * 128 + k; break;
      case 6: src = i_w;  idx = n * 256 + k; break;
      case 7: src = i_w;  idx = n * 256 + 128 + k; break;
      default: src = j_w; idx = n * 128 + k; break;
    }
    v = rd(src, idx);
  } else {
    int o = i - 217088;
    if (o < 384)      v = rd(b_ih, o);
    else if (o < 768) v = rd(b_hh, o - 384);
    else if (o < 896) v = rd(i_b, o - 768);
    else              v = rd(j_b, o - 896);
  }
  wb[i] = (bf16)v;
}

// ---------------------------------------------------------------------------
// CSR keyed by dst*4 + etype
// ---------------------------------------------------------------------------
__global__ __launch_bounds__(256) void hist_k(const int* __restrict__ dst,
                                              const int* __restrict__ ety,
                                              int* __restrict__ deg, int E)
{
  int e = blockIdx.x * 256 + threadIdx.x;
  if (e < E) atomicAdd(&deg[dst[e] * 4 + ety[e]], 1);
}

__global__ __launch_bounds__(512) void scan1_k(const int* __restrict__ deg, int* __restrict__ rp,
                                               int* __restrict__ part, int n)
{
  __shared__ int buf[512];
  int i = blockIdx.x * 512 + threadIdx.x;
  int v = (i < n) ? deg[i] : 0;
  buf[threadIdx.x] = v;
  __syncthreads();
#pragma unroll
  for (int off = 1; off < 512; off <<= 1) {
    int t = 0;
    if (threadIdx.x >= off) t = buf[threadIdx.x - off];
    __syncthreads();
    buf[threadIdx.x] += t;
    __syncthreads();
  }
  if (i < n) rp[i] = buf[threadIdx.x] - v;
  if (threadIdx.x == 511) part[blockIdx.x] = buf[511];
}

__global__ __launch_bounds__(1024) void scan2_k(int* __restrict__ part, int nb, int* __restrict__ total)
{
  __shared__ int buf[1024];
  int t0 = threadIdx.x;
  int v = (t0 < nb) ? part[t0] : 0;
  buf[t0] = v;
  __syncthreads();
#pragma unroll
  for (int off = 1; off < 1024; off <<= 1) {
    int t = 0;
    if (t0 >= off) t = buf[t0 - off];
    __syncthreads();
    buf[t0] += t;
    __syncthreads();
  }
  if (t0 < nb) part[t0] = buf[t0] - v;
  if (t0 == 1023) *total = buf[1023];
}

__global__ __launch_bounds__(512) void scan3_k(int* __restrict__ rp, const int* __restrict__ part, int n)
{
  int i = blockIdx.x * 512 + threadIdx.x;
  if (i < n) rp[i] += part[blockIdx.x];
}

// single-pass fill (round-9 verified, 86us).  ROUND-11 LESSON: two-pass
// bucketed variant regressed 4.4x (cross-XCD counter serialization; no
// temporal density).  Keep fine-grained atomics + direct scatter.
__global__ __launch_bounds__(256) void fill_k(const int* __restrict__ src, const int* __restrict__ dst,
                                              const int* __restrict__ ety, const int* __restrict__ rp,
                                              int* __restrict__ fil, int* __restrict__ bkt, int E)
{
  int e = blockIdx.x * 256 + threadIdx.x;
  if (e < E) {
    int key = dst[e] * 4 + ety[e];
    int pos = rp[key] + atomicAdd(&fil[key], 1);
    bkt[pos] = src[e];
  }
}

// ---------------------------------------------------------------------------
// standalone aggregate (round-8 verified) — used only in the ws-too-small
// fallback path.
// ---------------------------------------------------------------------------
__global__ __launch_bounds__(256) void agg_k(const bf16* __restrict__ hb,
                                             const int* __restrict__ rp,
                                             const int* __restrict__ bkt,
                                             bf16* __restrict__ aggH, int N)
{
  const int lane = threadIdx.x & 63;
  const int n = blockIdx.x * 4 + (threadIdx.x >> 6);
  if (n >= N) return;
  const unsigned* hp = (const unsigned*)hb;
  unsigned* outp = (unsigned*)aggH + (size_t)n * 272;
  const int e0 = rp[n * 4];
  const int e1 = rp[n * 4 + 1];
  const int e2 = rp[n * 4 + 2];
  const int e3 = rp[n * 4 + 3];
  const int e4 = rp[n * 4 + 4];

  float t0 = 0.f, t1 = 0.f;
  float s10 = 0.f, s11 = 0.f, s20 = 0.f, s21 = 0.f, s30 = 0.f, s31 = 0.f;

  int base = e0;
  for (; base + 8 <= e4; base += 8) {
    unsigned u[8];
#pragma unroll
    for (int t = 0; t < 8; ++t)
      u[t] = hp[(unsigned)bkt[base + t] * 64u + (unsigned)lane];
#pragma unroll
    for (int t = 0; t < 8; ++t) {
      const int i = base + t;
      t0 += __uint_as_float(u[t] << 16);
      t1 += __uint_as_float(u[t] & 0xffff0000u);
      s10 = (i < e1) ? t0 : s10;  s11 = (i < e1) ? t1 : s11;
      s20 = (i < e2) ? t0 : s20;  s21 = (i < e2) ? t1 : s21;
      s30 = (i < e3) ? t0 : s30;  s31 = (i < e3) ? t1 : s31;
    }
  }
  if (base < e4) {
    const int last = e4 - 1;
    unsigned u[8];
#pragma unroll
    for (int t = 0; t < 8; ++t) {
      int i = base + t; i = i <= last ? i : last;
      u[t] = hp[(unsigned)bkt[i] * 64u + (unsigned)lane];
    }
#pragma unroll
    for (int t = 0; t < 8; ++t) {
      const int i = base + t;
      const bool ok = (i <= last);
      const float v0 = __uint_as_float(u[t] << 16);
      const float v1 = __uint_as_float(u[t] & 0xffff0000u);
      t0 += ok ? v0 : 0.f;
      t1 += ok ? v1 : 0.f;
      s10 = (i < e1) ? t0 : s10;  s11 = (i < e1) ? t1 : s11;
      s20 = (i < e2) ? t0 : s20;  s21 = (i < e2) ? t1 : s21;
      s30 = (i < e3) ? t0 : s30;  s31 = (i < e3) ? t1 : s31;
    }
  }

  BP o;
  o.b[0] = (bf16)s10;         o.b[1] = (bf16)s11;         outp[0 * 64 + lane] = o.u;
  o.b[0] = (bf16)(s20 - s10); o.b[1] = (bf16)(s21 - s11); outp[1 * 64 + lane] = o.u;
  o.b[0] = (bf16)(s30 - s20); o.b[1] = (bf16)(s31 - s21); outp[2 * 64 + lane] = o.u;
  o.b[0] = (bf16)(t0 - s30);  o.b[1] = (bf16)(t1 - s31);  outp[3 * 64 + lane] = o.u;
  if (lane < 16) {
    BP z; z.b[0] = (bf16)0.f; z.b[1] = (bf16)0.f;
    if (lane == 0) { z.b[0] = (bf16)(float)(e1 - e0); z.b[1] = (bf16)(float)(e2 - e1); }
    if (lane == 1) { z.b[0] = (bf16)(float)(e3 - e2); z.b[1] = (bf16)(float)(e4 - e3); }
    outp[256 + lane] = z.u;
  }
}

// ---------------------------------------------------------------------------
extern "C" void kernel_launch(void* const* d_in, const int* in_sizes, int n_in,
                              void* d_out, int out_size, void* d_ws, size_t ws_size,
                              hipStream_t stream)
{
  const void* feat = d_in[0];
  const int*  src  = (const int*)d_in[1];
  const int*  dst  = (const int*)d_in[2];
  const int*  ety  = (const int*)d_in[3];

  const int N = in_sizes[0] / 128;   // 100000
  const int E = in_sizes[1];         // 1600000
  const int total = N * 128;

  // ---- workspace ----
  char* p = (char*)d_ws;
  auto alloc = [&](size_t bytes) -> char* {
    char* q = p;
    p += (bytes + 255) & ~(size_t)255;
    return q;
  };
  bf16* big  = (bf16*)alloc((size_t)N * 544 * 2);   // aggH [N,544]
  bf16* hb   = (bf16*)alloc((size_t)total * 2);     // h buffer A
  bf16* wb   = (bf16*)alloc(218112 * 2);
  int*  rp   = (int*) alloc(((size_t)4 * N + 1) * 4);
  int*  deg  = (int*) alloc((size_t)4 * N * 4);     // reused as fill counters
  int*  bkt  = (int*) alloc((size_t)E * 4);
  int*  part = (int*) alloc(1024 * 4);
  int*  flag = (int*) alloc(64);
  // optional h buffer B for the gather-fused ping-pong path
  size_t used = (size_t)(p - (char*)d_ws);
  const bool pp = (used + (size_t)total * 2 <= ws_size);
  bf16* hb1 = pp ? (bf16*)alloc((size_t)total * 2) : nullptr;

  const int gE  = (E + 255) / 256;
  const int gT  = (total + 255) / 256;
  const int gM  = (N + 127) / 128;
  const int n4  = 4 * N;
  const int gS  = (n4 + 511) / 512;

  // ---- dtype detect + canonicalize ----
  hipMemsetAsync(flag, 0, 4, stream);
  detect_k<<<1024, 256, 0, stream>>>((const unsigned short*)feat, 2000000, flag);
  feat_k<<<gT, 256, 0, stream>>>(feat, hb, total, flag);
  cvtw_k<<<(218112 + 255) / 256, 256, 0, stream>>>(
      d_in[4], d_in[5], d_in[6], d_in[7], d_in[8],
      d_in[9], d_in[10], d_in[11], d_in[12], d_in[13], wb, flag);

  // ---- CSR build ----
  hipMemsetAsync(deg, 0, (size_t)n4 * 4, stream);
  hist_k<<<gE, 256, 0, stream>>>(dst, ety, deg, E);
  scan1_k<<<gS, 512, 0, stream>>>(deg, rp, part, n4);
  scan2_k<<<1, 1024, 0, stream>>>(part, gS, rp + n4);
  scan3_k<<<gS, 512, 0, stream>>>(rp, part, n4);
  hipMemsetAsync(deg, 0, (size_t)n4 * 4, stream);
  fill_k<<<gE, 256, 0, stream>>>(src, dst, ety, rp, deg, bkt, E);

  const bf16* hfinal;
  if (pp) {
    // gather-fused path: ping-pong h so h' writes never race other blocks'
    // gather reads
    bf16* hin = hb; bf16* hout = hb1;
    for (int step = 0; step < 3; ++step) {
      fused2_k<<<gM, 256, 0, stream>>>(big, hin, hout, wb, rp, bkt, N, 1);
      bf16* t = hin; hin = hout; hout = t;
    }
    hfinal = hin;
  } else {
    // fallback: separate gather kernel, in-place h (tile-local writes only)
    for (int step = 0; step < 3; ++step) {
      agg_k<<<(N + 3) / 4, 256, 0, stream>>>(hb, rp, bkt, big, N);
      fused2_k<<<gM, 256, 0, stream>>>(big, hb, hb, wb, rp, bkt, N, 0);
    }
    hfinal = hb;
  }

  // ---- fused head ----
  headf_k<<<gM, 256, 0, stream>>>(hfinal, feat, wb, d_out, N, flag);
}

// Round 15
// 842.380 us; speedup vs baseline: 1.3215x; 1.3215x over previous
//
#include <hip/hip_runtime.h>
#include <hip/hip_bf16.h>

typedef __bf16 bf16;
typedef __attribute__((ext_vector_type(8))) __bf16 bf16x8;
typedef __attribute__((ext_vector_type(4))) float f32x4;

union BP { unsigned u; bf16 b[2]; };

#define SB() __builtin_amdgcn_sched_barrier(0)

// async global->LDS DMA, 16B per lane.  LDS dest is wave-uniform base +
// lane*16 (HW rule); global src is per-lane.  Tracked by vmcnt.
__device__ __forceinline__ void dma16(const void* g, void* l) {
  __builtin_amdgcn_global_load_lds(
      (const __attribute__((address_space(1))) unsigned*)g,
      (__attribute__((address_space(3))) unsigned*)l, 16, 0, 0);
}

// ---------------------------------------------------------------------------
// fully-fused step kernel: a = aggH @ Wcat -> GRU gate GEMMs -> GRU -> h'.
// Weight streams staged block-cooperatively into LDS via global_load_lds,
// double-buffered, counted vmcnt + raw s_barrier (round 9, verified).
// ROUND-14 LESSON (fused2_k revert): folding the gather phase into this
// kernel strangled it — the latency-bound gather needs agg_k's high block
// count (1 wave = 1 node, ~12.5K waves TLP); serializing 32 nodes per wave
// inside a 3-blocks/CU LDS-heavy kernel ran 254us vs 160us sequential.
// ---------------------------------------------------------------------------
__global__ __launch_bounds__(256) void fused_k(const bf16* __restrict__ big,
                                               bf16* __restrict__ hbp,
                                               const bf16* __restrict__ wb,
                                               int M)
{
  const int lane = threadIdx.x & 63;
  const int w    = threadIdx.x >> 6;
  const int quad = lane >> 4;
  const int lr   = lane & 15;
  const int mbase = blockIdx.x * 128 + w * 32;

  __shared__ __align__(16) bf16 lds[128 * 136];
  __shared__ __align__(16) bf16 wlds[2][4096];

  const bf16* wcat = wb;
  const bf16* blk  = wb + 69632;
  const bf16 *ih0 = blk,             *ih1 = blk + 16384, *ihn = blk + 2 * 16384;
  const bf16 *hh0 = blk + 3 * 16384, *hh1 = blk + 4 * 16384, *hhn = blk + 5 * 16384;
  const bf16 *bih = wb + 217088, *bhh = wb + 217472;

  long r0 = mbase + lr;      if (r0 >= M) r0 = M - 1;
  long r1 = mbase + 16 + lr; if (r1 >= M) r1 = M - 1;

  // ---- pass-1 prologue: issue group 0 (2 DMA + 2 A-loads = 4 vmcnt events)
  dma16(wcat + (size_t)(w * 2)     * 512 + (size_t)lane * 8, &wlds[0][(w * 2) * 512]);
  dma16(wcat + (size_t)(w * 2 + 1) * 512 + (size_t)lane * 8, &wlds[0][(w * 2 + 1) * 512]);
  bf16x8 Ab[2][2];
  Ab[0][0] = *(const bf16x8*)(big + r0 * 544 + quad * 8);
  Ab[0][1] = *(const bf16x8*)(big + r1 * 544 + quad * 8);

  f32x4 acc[2][8];
#pragma unroll
  for (int i = 0; i < 2; ++i)
#pragma unroll
    for (int j = 0; j < 8; ++j) acc[i][j] = (f32x4){0.f, 0.f, 0.f, 0.f};

  // ---- pass 1: a-tile (K=544); counted-vmcnt double-buffer pipeline ----
#pragma unroll
  for (int kk = 0; kk < 17; ++kk) {
    const int cur = kk & 1;
    const int nxt = cur ^ 1;
    if (kk + 1 < 17) {
      const size_t gb = (size_t)(kk + 1) * 4096;
      dma16(wcat + gb + (size_t)(w * 2)     * 512 + (size_t)lane * 8, &wlds[nxt][(w * 2) * 512]);
      dma16(wcat + gb + (size_t)(w * 2 + 1) * 512 + (size_t)lane * 8, &wlds[nxt][(w * 2 + 1) * 512]);
      const int kc = (kk + 1) * 32 + quad * 8;
      Ab[nxt][0] = *(const bf16x8*)(big + r0 * 544 + kc);
      Ab[nxt][1] = *(const bf16x8*)(big + r1 * 544 + kc);
    }
    SB();
    if (kk + 1 < 17) asm volatile("s_waitcnt vmcnt(4)" ::: "memory");
    else             asm volatile("s_waitcnt vmcnt(0)" ::: "memory");
    SB();
    __builtin_amdgcn_s_barrier();      // all waves' group-kk DMAs landed
    SB();
    __builtin_amdgcn_s_setprio(1);
#pragma unroll
    for (int ct = 0; ct < 8; ++ct) {
      bf16x8 b = *(const bf16x8*)&wlds[cur][(ct * 64 + lane) * 8];
      acc[0][ct] = __builtin_amdgcn_mfma_f32_16x16x32_bf16(Ab[cur][0], b, acc[0][ct], 0, 0, 0);
      acc[1][ct] = __builtin_amdgcn_mfma_f32_16x16x32_bf16(Ab[cur][1], b, acc[1][ct], 0, 0, 0);
    }
    __builtin_amdgcn_s_setprio(0);
    SB();
    __builtin_amdgcn_s_barrier();      // all waves done reading wlds[cur]
    SB();
  }

  // ---- gates prologue: DMA group (ch=0,kk=0) into buf0 ----
  const bf16* wptr0 = ih0; const bf16* wptr1 = hh0; const bf16* wptr2 = ih1;
  const bf16* wptr3 = hh1; const bf16* wptr4 = ihn; const bf16* wptr5 = hhn;
  {
    if (w == 0) { dma16(wptr0 + (size_t)lane * 8, &wlds[0][0 * 512]);
                  dma16(wptr4 + (size_t)lane * 8, &wlds[0][4 * 512]); }
    if (w == 1) { dma16(wptr1 + (size_t)lane * 8, &wlds[0][1 * 512]);
                  dma16(wptr5 + (size_t)lane * 8, &wlds[0][5 * 512]); }
    if (w == 2) { dma16(wptr2 + (size_t)lane * 8, &wlds[0][2 * 512]); }
    if (w == 3) { dma16(wptr3 + (size_t)lane * 8, &wlds[0][3 * 512]); }
  }

  // h fragments
  bf16x8 hf[2][4];
#pragma unroll
  for (int kk = 0; kk < 4; ++kk) {
    hf[0][kk] = *(const bf16x8*)(hbp + r0 * 128 + kk * 32 + quad * 8);
    hf[1][kk] = *(const bf16x8*)(hbp + r1 * 128 + kk * 32 + quad * 8);
  }
  // stage a-tile to LDS (wave-private rows; C/D-layout transpose)
#pragma unroll
  for (int ct = 0; ct < 8; ++ct) {
    const int nl = ct * 16 + lr;
#pragma unroll
    for (int rt = 0; rt < 2; ++rt) {
      const int rowb = w * 32 + rt * 16 + quad * 4;
#pragma unroll
      for (int r = 0; r < 4; ++r)
        lds[(rowb + r) * 136 + nl] = (bf16)acc[rt][ct][r];
    }
  }
  // wave reads only its own rows back -> ordered by lgkmcnt, no barrier
  bf16x8 af[2][4];
#pragma unroll
  for (int kk = 0; kk < 4; ++kk) {
    af[0][kk] = *(const bf16x8*)(lds + (w * 32 + lr) * 136 + kk * 32 + quad * 8);
    af[1][kk] = *(const bf16x8*)(lds + (w * 32 + 16 + lr) * 136 + kk * 32 + quad * 8);
  }
  // overwrite own rows with h-tile (row-major) for C/D-layout hv reads
#pragma unroll
  for (int kk = 0; kk < 4; ++kk) {
    *(bf16x8*)(lds + (w * 32 + lr) * 136 + kk * 32 + quad * 8)      = hf[0][kk];
    *(bf16x8*)(lds + (w * 32 + 16 + lr) * 136 + kk * 32 + quad * 8) = hf[1][kk];
  }
  __syncthreads();   // full drain: gates DMA(0) + hf loads + staging writes

  // ---- gates: 8 ch (rolled) x 4 kk (unrolled) counted-vmcnt phases ----
#pragma unroll 1
  for (int ch = 0; ch < 8; ++ch) {
    f32x4 c[4][2];   // [slice][rowfrag]: s0=r, s1=z, s2=in, s3=hn
#pragma unroll
    for (int s = 0; s < 4; ++s)
#pragma unroll
      for (int i = 0; i < 2; ++i) c[s][i] = (f32x4){0.f, 0.f, 0.f, 0.f};

#pragma unroll
    for (int kk = 0; kk < 4; ++kk) {
      const int cur = kk & 1;
      const int nx  = cur ^ 1;
      // issue next group; ALWAYS issue (clamped at the very end) so the
      // per-wave vmcnt event count stays uniform across phases
      {
        size_t koff;
        if (kk < 3) koff = (size_t)((kk + 1) * 8 + ch) * 512;
        else        koff = (size_t)(ch < 7 ? ch + 1 : 7) * 512;  // (kk=0, ct=ch+1); ch=7: dummy
        if (w == 0) { dma16(wptr0 + koff + (size_t)lane * 8, &wlds[nx][0 * 512]);
                      dma16(wptr4 + koff + (size_t)lane * 8, &wlds[nx][4 * 512]); }
        if (w == 1) { dma16(wptr1 + koff + (size_t)lane * 8, &wlds[nx][1 * 512]);
                      dma16(wptr5 + koff + (size_t)lane * 8, &wlds[nx][5 * 512]); }
        if (w == 2) { dma16(wptr2 + koff + (size_t)lane * 8, &wlds[nx][2 * 512]); }
        if (w == 3) { dma16(wptr3 + koff + (size_t)lane * 8, &wlds[nx][3 * 512]); }
      }
      SB();
      if (w < 2) asm volatile("s_waitcnt vmcnt(2)" ::: "memory");
      else       asm volatile("s_waitcnt vmcnt(1)" ::: "memory");
      SB();
      __builtin_amdgcn_s_barrier();    // all waves' current group landed
      SB();
      // consume current group from LDS
      bf16x8 g0 = *(const bf16x8*)&wlds[cur][(0 * 64 + lane) * 8];
      bf16x8 g1 = *(const bf16x8*)&wlds[cur][(1 * 64 + lane) * 8];
      bf16x8 g2 = *(const bf16x8*)&wlds[cur][(2 * 64 + lane) * 8];
      bf16x8 g3 = *(const bf16x8*)&wlds[cur][(3 * 64 + lane) * 8];
      bf16x8 g4 = *(const bf16x8*)&wlds[cur][(4 * 64 + lane) * 8];
      bf16x8 g5 = *(const bf16x8*)&wlds[cur][(5 * 64 + lane) * 8];
      __builtin_amdgcn_s_setprio(1);
      c[0][0] = __builtin_amdgcn_mfma_f32_16x16x32_bf16(af[0][kk], g0, c[0][0], 0, 0, 0);
      c[0][1] = __builtin_amdgcn_mfma_f32_16x16x32_bf16(af[1][kk], g0, c[0][1], 0, 0, 0);
      c[0][0] = __builtin_amdgcn_mfma_f32_16x16x32_bf16(hf[0][kk], g1, c[0][0], 0, 0, 0);
      c[0][1] = __builtin_amdgcn_mfma_f32_16x16x32_bf16(hf[1][kk], g1, c[0][1], 0, 0, 0);
      c[1][0] = __builtin_amdgcn_mfma_f32_16x16x32_bf16(af[0][kk], g2, c[1][0], 0, 0, 0);
      c[1][1] = __builtin_amdgcn_mfma_f32_16x16x32_bf16(af[1][kk], g2, c[1][1], 0, 0, 0);
      c[1][0] = __builtin_amdgcn_mfma_f32_16x16x32_bf16(hf[0][kk], g3, c[1][0], 0, 0, 0);
      c[1][1] = __builtin_amdgcn_mfma_f32_16x16x32_bf16(hf[1][kk], g3, c[1][1], 0, 0, 0);
      c[2][0] = __builtin_amdgcn_mfma_f32_16x16x32_bf16(af[0][kk], g4, c[2][0], 0, 0, 0);
      c[2][1] = __builtin_amdgcn_mfma_f32_16x16x32_bf16(af[1][kk], g4, c[2][1], 0, 0, 0);
      c[3][0] = __builtin_amdgcn_mfma_f32_16x16x32_bf16(hf[0][kk], g5, c[3][0], 0, 0, 0);
      c[3][1] = __builtin_amdgcn_mfma_f32_16x16x32_bf16(hf[1][kk], g5, c[3][1], 0, 0, 0);
      __builtin_amdgcn_s_setprio(0);

      if (kk == 3) {
        // GRU nonlinearity in registers; hv from LDS (wave-private rows)
        const int col = ch * 16 + lr;
        const float br = (float)bih[col]       + (float)bhh[col];
        const float bz = (float)bih[128 + col] + (float)bhh[128 + col];
        const float bi = (float)bih[256 + col];
        const float bh = (float)bhh[256 + col];
#pragma unroll
        for (int rt = 0; rt < 2; ++rt) {
          const int rowb = w * 32 + rt * 16 + quad * 4;
#pragma unroll
          for (int r = 0; r < 4; ++r) {
            const int li = (rowb + r) * 136 + col;
            const float hv = (float)lds[li];
            const float rr = 1.f / (1.f + __expf(-(c[0][rt][r] + br)));
            const float zz = 1.f / (1.f + __expf(-(c[1][rt][r] + bz)));
            const float xn = c[2][rt][r] + bi + rr * (c[3][rt][r] + bh);
            const float e2 = __expf(2.f * xn);
            const float nn = 1.f - 2.f / (e2 + 1.f);   // tanh(xn)
            lds[li] = (bf16)((1.f - zz) * nn + zz * hv);
          }
        }
      }
      SB();
      __builtin_amdgcn_s_barrier();    // all waves done reading wlds[cur]
      SB();
    }
  }

  __syncthreads();   // full drain (vm + lgkm) before cross-wave h' readback
  // coalesced h' store
  const int tr = threadIdx.x >> 4;
  const int tc = (threadIdx.x & 15) * 8;
#pragma unroll
  for (int i = 0; i < 8; ++i) {
    const int row = i * 16 + tr;
    const int grow = blockIdx.x * 128 + row;
    if (grow < M) {
      bf16x8 v = *(const bf16x8*)(lds + row * 136 + tc);
      *(bf16x8*)(hbp + (size_t)grow * 128 + tc) = v;
    }
  }
}

// ---------------------------------------------------------------------------
// fused output head (round-13, verified): gl = hb@iwa + feat@iwb + ib,
// u = hb@jw + jb, out = u*sigmoid(gl); f32 intermediates.
// ---------------------------------------------------------------------------
__global__ __launch_bounds__(256) void headf_k(const bf16* __restrict__ hbp,
                                               const void* __restrict__ featp,
                                               const bf16* __restrict__ wb,
                                               void* __restrict__ outp, int M,
                                               const int* __restrict__ flagp)
{
  const int lane = threadIdx.x & 63;
  const int w    = threadIdx.x >> 6;
  const int quad = lane >> 4;
  const int lr   = lane & 15;
  const int mbase = blockIdx.x * 128 + w * 32;

  __shared__ __align__(16) bf16 lds[128 * 136];
  __shared__ __align__(16) bf16 wlds[2][1536];

  const bf16* blk = wb + 69632;
  const bf16 *iwa = blk + 6 * 16384, *iwb = blk + 7 * 16384, *jw = blk + 8 * 16384;
  const bf16 *ib = wb + 217856, *jb = wb + 217984;
  const bool f32o = (*flagp != 0);

  long r0 = mbase + lr;      if (r0 >= M) r0 = M - 1;
  long r1 = mbase + 16 + lr; if (r1 >= M) r1 = M - 1;

  if (w == 0) dma16(iwa + (size_t)lane * 8, &wlds[0][0 * 512]);
  if (w == 1) dma16(iwb + (size_t)lane * 8, &wlds[0][1 * 512]);
  if (w == 2) dma16(jw  + (size_t)lane * 8, &wlds[0][2 * 512]);

  bf16x8 hf[2][4], ff[2][4];
#pragma unroll
  for (int kk = 0; kk < 4; ++kk) {
    hf[0][kk] = *(const bf16x8*)(hbp + r0 * 128 + kk * 32 + quad * 8);
    hf[1][kk] = *(const bf16x8*)(hbp + r1 * 128 + kk * 32 + quad * 8);
  }
  if (f32o) {
    const float* F = (const float*)featp;
#pragma unroll
    for (int kk = 0; kk < 4; ++kk) {
      const int kc = kk * 32 + quad * 8;
      f32x4 x0 = *(const f32x4*)(F + r0 * 128 + kc);
      f32x4 x1 = *(const f32x4*)(F + r0 * 128 + kc + 4);
      f32x4 y0 = *(const f32x4*)(F + r1 * 128 + kc);
      f32x4 y1 = *(const f32x4*)(F + r1 * 128 + kc + 4);
#pragma unroll
      for (int i = 0; i < 4; ++i) {
        ff[0][kk][i] = (bf16)x0[i]; ff[0][kk][i + 4] = (bf16)x1[i];
        ff[1][kk][i] = (bf16)y0[i]; ff[1][kk][i + 4] = (bf16)y1[i];
      }
    }
  } else {
    const bf16* F = (const bf16*)featp;
#pragma unroll
    for (int kk = 0; kk < 4; ++kk) {
      ff[0][kk] = *(const bf16x8*)(F + r0 * 128 + kk * 32 + quad * 8);
      ff[1][kk] = *(const bf16x8*)(F + r1 * 128 + kk * 32 + quad * 8);
    }
  }
  __syncthreads();   // full drain: DMA(0) + fragment loads

#pragma unroll 1
  for (int ch = 0; ch < 8; ++ch) {
    f32x4 cg[2], cu[2];
#pragma unroll
    for (int i = 0; i < 2; ++i) { cg[i] = (f32x4){0.f, 0.f, 0.f, 0.f};
                                  cu[i] = (f32x4){0.f, 0.f, 0.f, 0.f}; }
#pragma unroll
    for (int kk = 0; kk < 4; ++kk) {
      const int cur = kk & 1;
      const int nx  = cur ^ 1;
      {
        size_t koff;
        if (kk < 3) koff = (size_t)((kk + 1) * 8 + ch) * 512;
        else        koff = (size_t)(ch < 7 ? ch + 1 : 7) * 512;  // (kk=0); ch=7: dummy
        if (w == 0) dma16(iwa + koff + (size_t)lane * 8, &wlds[nx][0 * 512]);
        if (w == 1) dma16(iwb + koff + (size_t)lane * 8, &wlds[nx][1 * 512]);
        if (w == 2) dma16(jw  + koff + (size_t)lane * 8, &wlds[nx][2 * 512]);
      }
      SB();
      if (w < 3) asm volatile("s_waitcnt vmcnt(1)" ::: "memory");
      else       asm volatile("s_waitcnt vmcnt(0)" ::: "memory");
      SB();
      __builtin_amdgcn_s_barrier();    // all waves' current group landed
      SB();
      bf16x8 g0 = *(const bf16x8*)&wlds[cur][(0 * 64 + lane) * 8];
      bf16x8 g1 = *(const bf16x8*)&wlds[cur][(1 * 64 + lane) * 8];
      bf16x8 g2 = *(const bf16x8*)&wlds[cur][(2 * 64 + lane) * 8];
      __builtin_amdgcn_s_setprio(1);
      cg[0] = __builtin_amdgcn_mfma_f32_16x16x32_bf16(hf[0][kk], g0, cg[0], 0, 0, 0);
      cg[1] = __builtin_amdgcn_mfma_f32_16x16x32_bf16(hf[1][kk], g0, cg[1], 0, 0, 0);
      cg[0] = __builtin_amdgcn_mfma_f32_16x16x32_bf16(ff[0][kk], g1, cg[0], 0, 0, 0);
      cg[1] = __builtin_amdgcn_mfma_f32_16x16x32_bf16(ff[1][kk], g1, cg[1], 0, 0, 0);
      cu[0] = __builtin_amdgcn_mfma_f32_16x16x32_bf16(hf[0][kk], g2, cu[0], 0, 0, 0);
      cu[1] = __builtin_amdgcn_mfma_f32_16x16x32_bf16(hf[1][kk], g2, cu[1], 0, 0, 0);
      __builtin_amdgcn_s_setprio(0);

      if (kk == 3) {
        const int col = ch * 16 + lr;
        const float bg = (float)ib[col];
        const float bu = (float)jb[col];
#pragma unroll
        for (int rt = 0; rt < 2; ++rt) {
          const int rowb = w * 32 + rt * 16 + quad * 4;
#pragma unroll
          for (int r = 0; r < 4; ++r) {
            const float gl = cg[rt][r] + bg;
            const float uu = cu[rt][r] + bu;
            const float val = uu / (1.f + expf(-gl));
            if (f32o) {
              const int grow = blockIdx.x * 128 + rowb + r;
              if (grow < M)
                ((float*)outp)[(size_t)grow * 128 + col] = val;
            } else {
              lds[(rowb + r) * 136 + col] = (bf16)val;
            }
          }
        }
      }
      SB();
      __builtin_amdgcn_s_barrier();    // all waves done reading wlds[cur]
      SB();
    }
  }

  __syncthreads();
  if (!f32o) {
    const int tr = threadIdx.x >> 4;
    const int tc = (threadIdx.x & 15) * 8;
#pragma unroll
    for (int i = 0; i < 8; ++i) {
      const int row = i * 16 + tr;
      const int grow = blockIdx.x * 128 + row;
      if (grow < M) {
        bf16x8 v = *(const bf16x8*)(lds + row * 136 + tc);
        *(bf16x8*)((bf16*)outp + (size_t)grow * 128 + tc) = v;
      }
    }
  }
}

// ---------------------------------------------------------------------------
__global__ __launch_bounds__(256) void detect_k(const unsigned short* __restrict__ f,
                                                int n16, int* __restrict__ flag)
{
  int i = blockIdx.x * 256 + threadIdx.x;
  int bad = 0;
  for (int j = i; j < n16; j += 256 * 1024) {
    int ex = (f[j] >> 7) & 0xFF;
    if (ex >= 0x87) bad = 1;
  }
  if (bad) atomicAdd(flag, 1);
}

__global__ __launch_bounds__(256) void feat_k(const void* __restrict__ src,
                                              bf16* __restrict__ hb, int n,
                                              const int* __restrict__ flag)
{
  int i = blockIdx.x * 256 + threadIdx.x;
  if (i >= n) return;
  if (*flag) hb[i] = (bf16)((const float*)src)[i];
  else       hb[i] = ((const bf16*)src)[i];
}

// ---------------------------------------------------------------------------
__global__ __launch_bounds__(256) void cvtw_k(
    const void* w_et, const void* b_et, const void* w_ih, const void* b_ih,
    const void* w_hh, const void* b_hh, const void* i_w, const void* i_b,
    const void* j_w, const void* j_b, bf16* __restrict__ wb,
    const int* __restrict__ flagp)
{
  int i = blockIdx.x * 256 + threadIdx.x;
  if (i >= 218112) return;
  const bool f32 = (*flagp != 0);
  auto rd = [&](const void* p, int idx) -> float {
    return f32 ? ((const float*)p)[idx] : (float)((const bf16*)p)[idx];
  };
  float v;
  if (i < 69632) {
    int e = i, j = e & 7, lane = (e >> 3) & 63, ct = (e >> 9) & 7, kk = e >> 12;
    int n = ct * 16 + (lane & 15), k = kk * 32 + (lane >> 4) * 8 + j;
    if (k < 512)      v = rd(w_et, (k >> 7) * 16384 + n * 128 + (k & 127));
    else if (k < 516) v = rd(b_et, (k - 512) * 128 + n);
    else              v = 0.f;
  } else if (i < 217088) {
    int blk = (i - 69632) >> 14, e = (i - 69632) & 16383;
    int j = e & 7, lane = (e >> 3) & 63, ct = (e >> 9) & 7, kk = e >> 12;
    int n = ct * 16 + (lane & 15), k = kk * 32 + (lane >> 4) * 8 + j;
    const void* src; int idx;
    switch (blk) {
      case 0: src = w_ih; idx = n * 128 + k; break;
      case 1: src = w_ih; idx = (128 + n) * 128 + k; break;
      case 2: src = w_ih; idx = (256 + n) * 128 + k; break;
      case 3: src = w_hh; idx = n * 128 + k; break;
      case 4: src = w_hh; idx = (128 + n) * 128 + k; break;
      case 5: src = w_hh; idx = (256 + n) * 128 + k; break;
      case 6: src = i_w;  idx = n * 256 + k; break;
      case 7: src = i_w;  idx = n * 256 + 128 + k; break;
      default: src = j_w; idx = n * 128 + k; break;
    }
    v = rd(src, idx);
  } else {
    int o = i - 217088;
    if (o < 384)      v = rd(b_ih, o);
    else if (o < 768) v = rd(b_hh, o - 384);
    else if (o < 896) v = rd(i_b, o - 768);
    else              v = rd(j_b, o - 896);
  }
  wb[i] = (bf16)v;
}

// ---------------------------------------------------------------------------
// CSR keyed by dst*4 + etype
// ---------------------------------------------------------------------------
__global__ __launch_bounds__(256) void hist_k(const int* __restrict__ dst,
                                              const int* __restrict__ ety,
                                              int* __restrict__ deg, int E)
{
  int e = blockIdx.x * 256 + threadIdx.x;
  if (e < E) atomicAdd(&deg[dst[e] * 4 + ety[e]], 1);
}

__global__ __launch_bounds__(512) void scan1_k(const int* __restrict__ deg, int* __restrict__ rp,
                                               int* __restrict__ part, int n)
{
  __shared__ int buf[512];
  int i = blockIdx.x * 512 + threadIdx.x;
  int v = (i < n) ? deg[i] : 0;
  buf[threadIdx.x] = v;
  __syncthreads();
#pragma unroll
  for (int off = 1; off < 512; off <<= 1) {
    int t = 0;
    if (threadIdx.x >= off) t = buf[threadIdx.x - off];
    __syncthreads();
    buf[threadIdx.x] += t;
    __syncthreads();
  }
  if (i < n) rp[i] = buf[threadIdx.x] - v;
  if (threadIdx.x == 511) part[blockIdx.x] = buf[511];
}

__global__ __launch_bounds__(1024) void scan2_k(int* __restrict__ part, int nb, int* __restrict__ total)
{
  __shared__ int buf[1024];
  int t0 = threadIdx.x;
  int v = (t0 < nb) ? part[t0] : 0;
  buf[t0] = v;
  __syncthreads();
#pragma unroll
  for (int off = 1; off < 1024; off <<= 1) {
    int t = 0;
    if (t0 >= off) t = buf[t0 - off];
    __syncthreads();
    buf[t0] += t;
    __syncthreads();
  }
  if (t0 < nb) part[t0] = buf[t0] - v;
  if (t0 == 1023) *total = buf[1023];
}

__global__ __launch_bounds__(512) void scan3_k(int* __restrict__ rp, const int* __restrict__ part, int n)
{
  int i = blockIdx.x * 512 + threadIdx.x;
  if (i < n) rp[i] += part[blockIdx.x];
}

// single-pass fill (round-9 verified, 86us).  ROUND-11 LESSON: two-pass
// bucketed variant regressed 4.4x (cross-XCD counter serialization; no
// temporal density).  Keep fine-grained atomics + direct scatter.
__global__ __launch_bounds__(256) void fill_k(const int* __restrict__ src, const int* __restrict__ dst,
                                              const int* __restrict__ ety, const int* __restrict__ rp,
                                              int* __restrict__ fil, int* __restrict__ bkt, int E)
{
  int e = blockIdx.x * 256 + threadIdx.x;
  if (e < E) {
    int key = dst[e] * 4 + ety[e];
    int pos = rp[key] + atomicAdd(&fil[key], 1);
    bkt[pos] = src[e];
  }
}

// ---------------------------------------------------------------------------
// aggregate raw h per (dst, etype) -> aggH[n, 544]  (round-8 verified:
// prefix-sum snapshots, bit-op bf16->f32, 32-bit addressing, split tail).
// 1 wave = 1 node: the high block count IS the latency hiding (round-14
// lesson: folding this into the LDS-heavy GEMM kernel strangled its TLP).
// ---------------------------------------------------------------------------
__global__ __launch_bounds__(256) void agg_k(const bf16* __restrict__ hb,
                                             const int* __restrict__ rp,
                                             const int* __restrict__ bkt,
                                             bf16* __restrict__ aggH, int N)
{
  const int lane = threadIdx.x & 63;
  const int n = blockIdx.x * 4 + (threadIdx.x >> 6);
  if (n >= N) return;
  const unsigned* hp = (const unsigned*)hb;
  unsigned* outp = (unsigned*)aggH + (size_t)n * 272;
  const int e0 = rp[n * 4];
  const int e1 = rp[n * 4 + 1];
  const int e2 = rp[n * 4 + 2];
  const int e3 = rp[n * 4 + 3];
  const int e4 = rp[n * 4 + 4];

  float t0 = 0.f, t1 = 0.f;
  float s10 = 0.f, s11 = 0.f, s20 = 0.f, s21 = 0.f, s30 = 0.f, s31 = 0.f;

  int base = e0;
  for (; base + 8 <= e4; base += 8) {
    unsigned u[8];
#pragma unroll
    for (int t = 0; t < 8; ++t)
      u[t] = hp[(unsigned)bkt[base + t] * 64u + (unsigned)lane];
#pragma unroll
    for (int t = 0; t < 8; ++t) {
      const int i = base + t;
      t0 += __uint_as_float(u[t] << 16);
      t1 += __uint_as_float(u[t] & 0xffff0000u);
      s10 = (i < e1) ? t0 : s10;  s11 = (i < e1) ? t1 : s11;
      s20 = (i < e2) ? t0 : s20;  s21 = (i < e2) ? t1 : s21;
      s30 = (i < e3) ? t0 : s30;  s31 = (i < e3) ? t1 : s31;
    }
  }
  if (base < e4) {
    const int last = e4 - 1;
    unsigned u[8];
#pragma unroll
    for (int t = 0; t < 8; ++t) {
      int i = base + t; i = i <= last ? i : last;
      u[t] = hp[(unsigned)bkt[i] * 64u + (unsigned)lane];
    }
#pragma unroll
    for (int t = 0; t < 8; ++t) {
      const int i = base + t;
      const bool ok = (i <= last);
      const float v0 = __uint_as_float(u[t] << 16);
      const float v1 = __uint_as_float(u[t] & 0xffff0000u);
      t0 += ok ? v0 : 0.f;
      t1 += ok ? v1 : 0.f;
      s10 = (i < e1) ? t0 : s10;  s11 = (i < e1) ? t1 : s11;
      s20 = (i < e2) ? t0 : s20;  s21 = (i < e2) ? t1 : s21;
      s30 = (i < e3) ? t0 : s30;  s31 = (i < e3) ? t1 : s31;
    }
  }

  BP o;
  o.b[0] = (bf16)s10;         o.b[1] = (bf16)s11;         outp[0 * 64 + lane] = o.u;
  o.b[0] = (bf16)(s20 - s10); o.b[1] = (bf16)(s21 - s11); outp[1 * 64 + lane] = o.u;
  o.b[0] = (bf16)(s30 - s20); o.b[1] = (bf16)(s31 - s21); outp[2 * 64 + lane] = o.u;
  o.b[0] = (bf16)(t0 - s30);  o.b[1] = (bf16)(t1 - s31);  outp[3 * 64 + lane] = o.u;
  if (lane < 16) {
    BP z; z.b[0] = (bf16)0.f; z.b[1] = (bf16)0.f;
    if (lane == 0) { z.b[0] = (bf16)(float)(e1 - e0); z.b[1] = (bf16)(float)(e2 - e1); }
    if (lane == 1) { z.b[0] = (bf16)(float)(e3 - e2); z.b[1] = (bf16)(float)(e4 - e3); }
    outp[256 + lane] = z.u;
  }
}

// ---------------------------------------------------------------------------
extern "C" void kernel_launch(void* const* d_in, const int* in_sizes, int n_in,
                              void* d_out, int out_size, void* d_ws, size_t ws_size,
                              hipStream_t stream)
{
  const void* feat = d_in[0];
  const int*  src  = (const int*)d_in[1];
  const int*  dst  = (const int*)d_in[2];
  const int*  ety  = (const int*)d_in[3];

  const int N = in_sizes[0] / 128;   // 100000
  const int E = in_sizes[1];         // 1600000
  const int total = N * 128;

  // ---- workspace ----
  char* p = (char*)d_ws;
  auto alloc = [&](size_t bytes) -> char* {
    char* q = p;
    p += (bytes + 255) & ~(size_t)255;
    return q;
  };
  bf16* big  = (bf16*)alloc((size_t)N * 544 * 2);   // aggH [N,544]
  bf16* hb   = (bf16*)alloc((size_t)total * 2);     // h (bf16)
  bf16* wb   = (bf16*)alloc(218112 * 2);
  int*  rp   = (int*) alloc(((size_t)4 * N + 1) * 4);
  int*  deg  = (int*) alloc((size_t)4 * N * 4);     // reused as fill counters
  int*  bkt  = (int*) alloc((size_t)E * 4);
  int*  part = (int*) alloc(1024 * 4);
  int*  flag = (int*) alloc(64);

  const int gE  = (E + 255) / 256;
  const int gT  = (total + 255) / 256;
  const int gM  = (N + 127) / 128;
  const int n4  = 4 * N;
  const int gS  = (n4 + 511) / 512;

  // ---- dtype detect + canonicalize ----
  hipMemsetAsync(flag, 0, 4, stream);
  detect_k<<<1024, 256, 0, stream>>>((const unsigned short*)feat, 2000000, flag);
  feat_k<<<gT, 256, 0, stream>>>(feat, hb, total, flag);
  cvtw_k<<<(218112 + 255) / 256, 256, 0, stream>>>(
      d_in[4], d_in[5], d_in[6], d_in[7], d_in[8],
      d_in[9], d_in[10], d_in[11], d_in[12], d_in[13], wb, flag);

  // ---- CSR build ----
  hipMemsetAsync(deg, 0, (size_t)n4 * 4, stream);
  hist_k<<<gE, 256, 0, stream>>>(dst, ety, deg, E);
  scan1_k<<<gS, 512, 0, stream>>>(deg, rp, part, n4);
  scan2_k<<<1, 1024, 0, stream>>>(part, gS, rp + n4);
  scan3_k<<<gS, 512, 0, stream>>>(rp, part, n4);
  hipMemsetAsync(deg, 0, (size_t)n4 * 4, stream);
  fill_k<<<gE, 256, 0, stream>>>(src, dst, ety, rp, deg, bkt, E);

  for (int step = 0; step < 3; ++step) {
    agg_k<<<(N + 3) / 4, 256, 0, stream>>>(hb, rp, bkt, big, N);
    fused_k<<<gM, 256, 0, stream>>>(big, hb, wb, N);
  }

  // ---- fused head ----
  headf_k<<<gM, 256, 0, stream>>>(hb, feat, wb, d_out, N, flag);
}